// Round 9
// baseline (207.280 us; speedup 1.0000x reference)
//
#include <hip/hip_runtime.h>
#include <hip/hip_bf16.h>

#define NUM_BUCKETS 8192

typedef float f32x4 __attribute__((ext_vector_type(4)));

// Kernel 1: exclusive prefix sum of row_lengths -> offs[0..B].
// Single block, 1024 threads, 16 elems/thread, shfl-based (~4 barriers/chunk).
__global__ __launch_bounds__(1024) void scan_rows_kernel(
    const int* __restrict__ row_len, int* __restrict__ offs, int B) {
    __shared__ int wave_sums[16];
    __shared__ int carry_s;
    const int t = threadIdx.x;
    const int wave = t >> 6, lane = t & 63;
    if (t == 0) carry_s = 0;
    __syncthreads();
    const int CHUNK = 1024 * 16;
    for (int base = 0; base < B; base += CHUNK) {
        int v[16];
        const int idx0 = base + t * 16;
        int local = 0;
        #pragma unroll
        for (int e = 0; e < 16; ++e) {
            const int i = idx0 + e;
            const int x = (i < B) ? row_len[i] : 0;
            v[e] = local;          // exclusive within thread
            local += x;
        }
        int incl = local;
        #pragma unroll
        for (int d = 1; d < 64; d <<= 1) {
            const int y = __shfl_up(incl, d, 64);
            if (lane >= d) incl += y;
        }
        if (lane == 63) wave_sums[wave] = incl;
        __syncthreads();
        if (wave == 0) {
            int s = (lane < 16) ? wave_sums[lane] : 0;
            #pragma unroll
            for (int d = 1; d < 16; d <<= 1) {
                const int y = __shfl_up(s, d, 64);
                if (lane >= d) s += y;
            }
            if (lane < 16) wave_sums[lane] = s;
        }
        __syncthreads();
        const int carry = carry_s;
        const int wave_excl = (wave == 0) ? 0 : wave_sums[wave - 1];
        const int texcl = carry + wave_excl + (incl - local);
        #pragma unroll
        for (int e = 0; e < 16; ++e) {
            const int i = idx0 + e;
            if (i < B) offs[i] = texcl + v[e];
        }
        if (t == 0 && base + CHUNK >= B) offs[B] = carry + wave_sums[15];
        __syncthreads();
        if (t == 0) carry_s = carry + wave_sums[15];
        __syncthreads();
    }
}

// Kernel 2: pure zero-fill of the whole output — EXACTLY the rocclr
// fillBufferAligned shape (persistent grid-stride waves, register-source
// dwordx4 stores, no LDS, no barriers, no waitcnt on the store path).
// Measured 6.6 TB/s at ~10% occupancy on this chip.
__global__ __launch_bounds__(256) void zero_fill_kernel(
    float* __restrict__ out, long long nvec) {
    f32x4* ov = reinterpret_cast<f32x4*>(out);
    const f32x4 z = {0.f, 0.f, 0.f, 0.f};
    const long long stride = (long long)gridDim.x * 256;
    for (long long i = (long long)blockIdx.x * 256 + threadIdx.x; i < nvec;
         i += stride)
        ov[i] = z;
}

// Kernel 3: scatter. One 64-thread block per row, <=50 global fp32 atomics
// into the freshly zeroed row. Kernel boundary (stream order) guarantees the
// zeros are visible — no in-kernel store-queue waits anywhere. Duplicate ids
// handled exactly by the atomics. No LDS, tiny VGPR -> up to 32 resident
// 1-wave blocks/CU, so the RMW latency is fully overlapped.
__global__ __launch_bounds__(64) void scatter_kernel(
    const int* __restrict__ ids, const float* __restrict__ w,
    const int* __restrict__ offs, float* __restrict__ out) {
    const int r = blockIdx.x;
    const int t = threadIdx.x;
    const int s = offs[r];
    const int e = offs[r + 1];
    float* rowp = out + (size_t)r * NUM_BUCKETS;
    for (int i = s + t; i < e; i += 64)
        atomicAdd(&rowp[ids[i]], w[i]);
}

extern "C" void kernel_launch(void* const* d_in, const int* in_sizes, int n_in,
                              void* d_out, int out_size, void* d_ws, size_t ws_size,
                              hipStream_t stream) {
    const int*   ids     = (const int*)d_in[0];    // values (NNZ,1) int32
    const int*   row_len = (const int*)d_in[1];    // row_lengths (B,1) int32
    const float* wvals   = (const float*)d_in[2];  // weight_values (NNZ,1) f32
    // d_in[3] = weight_row_lengths (unused by reference)

    const int B = in_sizes[1];
    float* out = (float*)d_out;
    int* offs = (int*)d_ws;  // needs (B+1)*4 bytes

    scan_rows_kernel<<<1, 1024, 0, stream>>>(row_len, offs, B);

    const long long nvec = (long long)out_size / 4;  // f32x4 count
    zero_fill_kernel<<<2048, 256, 0, stream>>>(out, nvec);

    scatter_kernel<<<B, 64, 0, stream>>>(ids, wvals, offs, out);
}

// Round 10
// 126.440 us; speedup vs baseline: 1.6394x; 1.6394x over previous
//
#include <hip/hip_runtime.h>
#include <hip/hip_bf16.h>

#define NUM_BUCKETS 8192
#define ROW_THREADS 512  // 8 waves/block, 4 blocks/CU -> 32 waves/CU (the cap)

typedef float f32x4 __attribute__((ext_vector_type(4)));

// Kernel 1: exclusive prefix sum of row_lengths -> offs[0..B].
// Single block, 1024 threads, 16 elems/thread, shfl-based (~4 barriers/chunk).
__global__ __launch_bounds__(1024) void scan_rows_kernel(
    const int* __restrict__ row_len, int* __restrict__ offs, int B) {
    __shared__ int wave_sums[16];
    __shared__ int carry_s;
    const int t = threadIdx.x;
    const int wave = t >> 6, lane = t & 63;
    if (t == 0) carry_s = 0;
    __syncthreads();
    const int CHUNK = 1024 * 16;
    for (int base = 0; base < B; base += CHUNK) {
        int v[16];
        const int idx0 = base + t * 16;
        int local = 0;
        #pragma unroll
        for (int e = 0; e < 16; ++e) {
            const int i = idx0 + e;
            const int x = (i < B) ? row_len[i] : 0;
            v[e] = local;          // exclusive within thread
            local += x;
        }
        int incl = local;
        #pragma unroll
        for (int d = 1; d < 64; d <<= 1) {
            const int y = __shfl_up(incl, d, 64);
            if (lane >= d) incl += y;
        }
        if (lane == 63) wave_sums[wave] = incl;
        __syncthreads();
        if (wave == 0) {
            int s = (lane < 16) ? wave_sums[lane] : 0;
            #pragma unroll
            for (int d = 1; d < 16; d <<= 1) {
                const int y = __shfl_up(s, d, 64);
                if (lane >= d) s += y;
            }
            if (lane < 16) wave_sums[lane] = s;
        }
        __syncthreads();
        const int carry = carry_s;
        const int wave_excl = (wave == 0) ? 0 : wave_sums[wave - 1];
        const int texcl = carry + wave_excl + (incl - local);
        #pragma unroll
        for (int e = 0; e < 16; ++e) {
            const int i = idx0 + e;
            if (i < B) offs[i] = texcl + v[e];
        }
        if (t == 0 && base + CHUNK >= B) offs[B] = carry + wave_sums[15];
        __syncthreads();
        if (t == 0) carry_s = carry + wave_sums[15];
        __syncthreads();
    }
}

// Kernel 2: one block per row (proven R6 shape), 512 threads. Payload loads
// hoisted before the LDS zero (latency hides under it); plain coalesced
// dwordx4 stores; no waitcnt on the store path; block exits with stores
// in flight. Only change vs the 118 us kernel: ROW_THREADS 256 -> 512
// (32 waves/CU instead of 20) to deepen store-issue overlap.
__global__ __launch_bounds__(ROW_THREADS) void nhot_row_kernel(
    const int* __restrict__ ids, const float* __restrict__ w,
    const int* __restrict__ offs, float* __restrict__ out) {
    __shared__ float lds[NUM_BUCKETS];
    const int r = blockIdx.x;
    const int t = threadIdx.x;

    // issue payload loads first; they complete while we zero LDS
    const int s = offs[r];
    const int e = offs[r + 1];
    const int n = e - s;
    int id = 0; float wt = 0.f;
    if (t < n) { id = ids[s + t]; wt = w[s + t]; }

    f32x4* ldsv = reinterpret_cast<f32x4*>(lds);
    const f32x4 z = {0.f, 0.f, 0.f, 0.f};
    #pragma unroll
    for (int k = 0; k < NUM_BUCKETS / 4 / ROW_THREADS; ++k)  // 4 x ds_write_b128
        ldsv[k * ROW_THREADS + t] = z;
    __syncthreads();

    if (t < n) atomicAdd(&lds[id], wt);
    for (int i = s + t + ROW_THREADS; i < e; i += ROW_THREADS)  // general tail
        atomicAdd(&lds[ids[i]], w[i]);
    __syncthreads();

    f32x4* outv = reinterpret_cast<f32x4*>(out + (size_t)r * NUM_BUCKETS);
    #pragma unroll
    for (int k = 0; k < NUM_BUCKETS / 4 / ROW_THREADS; ++k)  // 4 x dwordx4
        outv[k * ROW_THREADS + t] = ldsv[k * ROW_THREADS + t];
}

extern "C" void kernel_launch(void* const* d_in, const int* in_sizes, int n_in,
                              void* d_out, int out_size, void* d_ws, size_t ws_size,
                              hipStream_t stream) {
    const int*   ids     = (const int*)d_in[0];    // values (NNZ,1) int32
    const int*   row_len = (const int*)d_in[1];    // row_lengths (B,1) int32
    const float* wvals   = (const float*)d_in[2];  // weight_values (NNZ,1) f32
    // d_in[3] = weight_row_lengths (unused by reference)

    const int B = in_sizes[1];
    float* out = (float*)d_out;
    int* offs = (int*)d_ws;  // needs (B+1)*4 bytes

    scan_rows_kernel<<<1, 1024, 0, stream>>>(row_len, offs, B);
    nhot_row_kernel<<<B, ROW_THREADS, 0, stream>>>(ids, wvals, offs, out);
}